// Round 1
// baseline (290.265 us; speedup 1.0000x reference)
//
#include <hip/hip_runtime.h>

#define NN 50000
#define EE 1600000
#define INF 128
#define OUTF 64
#define NH 2
#define ALPHA 0.2f

#define NSPREP 391        // sprep blocks (128 rows each)
#define NWPREP 64         // wprep blocks
#define NBNODE 391        // GEMM blocks (128 rows each)
#define NEBLK 1024        // edge-pass blocks

typedef __attribute__((ext_vector_type(8))) short s16x8;
typedef __attribute__((ext_vector_type(4))) float f32x4;

__device__ __forceinline__ unsigned short bf16_rne(float f) {
    union { float f; unsigned u; } v; v.f = f;
    unsigned r = v.u + 0x7FFFu + ((v.u >> 16) & 1u);
    return (unsigned short)(r >> 16);
}
__device__ __forceinline__ float bf16_val(unsigned short h) {
    union { unsigned u; float f; } v; v.u = ((unsigned)h) << 16;
    return v.f;
}
__device__ __forceinline__ void split8(const float4 a, const float4 b,
                                       s16x8& hi, s16x8& lo) {
    const float p[8] = {a.x, a.y, a.z, a.w, b.x, b.y, b.z, b.w};
    #pragma unroll
    for (int j = 0; j < 8; ++j) {
        const unsigned short h = bf16_rne(p[j]);
        hi[j] = (short)h;
        lo[j] = (short)bf16_rne(p[j] - bf16_val(h));
    }
}

// ws layout (floats):
//   si      [0      , 100000)
//   sj      [100000 , 200000)
//   attnsum [200000 , 400000)   2 floats per node, zeroed by K1
//   Z       [400000 , 400002)   zeroed by K1 (contiguous with attnsum)
//   Wf      [400064 , 416448)   32768 ushorts: 8 B-tiles hi | 8 lo

// K1: blocks [0,NSPREP)         : s_i/s_j = x.(W.a) fp32 GEMV
//     blocks [NSPREP, +NWPREP)  : W -> split-bf16 B-fragments + zero attnsum/Z
__global__ __launch_bounds__(256)
void gat_prep(const float* __restrict__ x, const float* __restrict__ Wg,
              const float* __restrict__ av,
              float* __restrict__ si, float* __restrict__ sj,
              unsigned short* __restrict__ Wf, float* __restrict__ azero)
{
    __shared__ float4 u4[128];   // {ui_h0, uj_h0, ui_h1, uj_h1} per k
    const int tid = threadIdx.x;

    if (blockIdx.x >= NSPREP) {           // ---- wprep + zero path ----
        const int idx = (blockIdx.x - NSPREP) * 256 + tid;  // 0..16383
        // zero attnsum (200000) + Z (2), contiguous
        for (int j = idx; j < 200002; j += NWPREP * 256)
            azero[j] = 0.0f;
        const int h = idx >> 13;          // W flat = h*8192 + k*64 + o
        const int k = (idx >> 6) & 127;
        const int o = idx & 63;
        const float w = Wg[idx];
        const unsigned short hi = bf16_rne(w);
        const unsigned short lo = bf16_rne(w - bf16_val(hi));
        const int n  = h * 64 + o;        // fused col (head-major)
        const int nt = n >> 4;
        const int ks = k >> 5;
        const int kk = k & 31;
        const int ln = (kk >> 3) * 16 + (n & 15);
        const int pos = ((nt * 4 + ks) * 64 + ln) * 8 + (kk & 7);
        Wf[pos] = hi;
        Wf[16384 + pos] = lo;
        return;
    }

    // ---- sprep path: scores via u = W.a (per-block, L2-hot) ----
    if (tid < 128) {
        const int k = tid;
        float u0 = 0.f, u1 = 0.f, u2 = 0.f, u3 = 0.f;
        #pragma unroll 4
        for (int o = 0; o < 64; o += 4) {
            const float4 w0 = *(const float4*)&Wg[k * 64 + o];
            const float4 w1 = *(const float4*)&Wg[8192 + k * 64 + o];
            const float4 ai0 = *(const float4*)&av[o];
            const float4 aj0 = *(const float4*)&av[64 + o];
            const float4 ai1 = *(const float4*)&av[128 + o];
            const float4 aj1 = *(const float4*)&av[192 + o];
            u0 += w0.x*ai0.x + w0.y*ai0.y + w0.z*ai0.z + w0.w*ai0.w;
            u1 += w0.x*aj0.x + w0.y*aj0.y + w0.z*aj0.z + w0.w*aj0.w;
            u2 += w1.x*ai1.x + w1.y*ai1.y + w1.z*ai1.z + w1.w*ai1.w;
            u3 += w1.x*aj1.x + w1.y*aj1.y + w1.z*aj1.z + w1.w*aj1.w;
        }
        u4[k] = make_float4(u0, u1, u2, u3);
    }
    __syncthreads();

    const int lane = tid & 63;
    const int wv = tid >> 6;
    const int lm = lane & 15;
    const int rsub = lane >> 4;           // 4 rows per wave

    #pragma unroll
    for (int p = 0; p < 8; ++p) {         // 128 rows/block
        const int row = blockIdx.x * 128 + p * 16 + wv * 4 + rsub;
        const int rc = row < NN ? row : NN - 1;
        const float4 xa = *(const float4*)(x + (size_t)rc * INF + lm * 8);
        const float4 xb = *(const float4*)(x + (size_t)rc * INF + lm * 8 + 4);
        float s0 = 0.f, s1 = 0.f, s2 = 0.f, s3 = 0.f;
        const float xv[8] = {xa.x, xa.y, xa.z, xa.w, xb.x, xb.y, xb.z, xb.w};
        #pragma unroll
        for (int j = 0; j < 8; ++j) {
            const float4 u = u4[lm * 8 + j];
            s0 = fmaf(xv[j], u.x, s0);
            s1 = fmaf(xv[j], u.y, s1);
            s2 = fmaf(xv[j], u.z, s2);
            s3 = fmaf(xv[j], u.w, s3);
        }
        #pragma unroll
        for (int m = 1; m < 16; m <<= 1) {
            s0 += __shfl_xor(s0, m, 64);
            s1 += __shfl_xor(s1, m, 64);
            s2 += __shfl_xor(s2, m, 64);
            s3 += __shfl_xor(s3, m, 64);
        }
        if (lm == 0 && row < NN) {
            *(float2*)&si[2 * row] = make_float2(s0, s2);
            *(float2*)&sj[2 * row] = make_float2(s1, s3);
        }
    }
}

// K2: streaming edge pass — gather scores, exp, direct global atomic
// accumulation into attnsum[dst] + hierarchical Z reduction.
__global__ __launch_bounds__(256)
void gat_edge(const int* __restrict__ ei,
              const float* __restrict__ si, const float* __restrict__ sj,
              float* __restrict__ attnsum, float* __restrict__ Z)
{
    __shared__ float zr0[4], zr1[4];
    const int gid = blockIdx.x * 256 + threadIdx.x;
    const int gsz = gridDim.x * 256;
    const int4* src4 = (const int4*)ei;
    const int4* dst4 = (const int4*)(ei + EE);

    float z0 = 0.f, z1 = 0.f;
    for (int i = gid; i < EE / 4; i += gsz) {
        const int4 s4 = src4[i];
        const int4 d4 = dst4[i];
        const int ss[4] = {s4.x, s4.y, s4.z, s4.w};
        const int dd[4] = {d4.x, d4.y, d4.z, d4.w};
        #pragma unroll
        for (int k = 0; k < 4; ++k) {
            const float2 vi = *(const float2*)&si[2 * ss[k]];
            const float2 vj = *(const float2*)&sj[2 * dd[k]];
            float a0 = vi.x + vj.x; a0 = a0 > 0.f ? a0 : ALPHA * a0;
            float a1 = vi.y + vj.y; a1 = a1 > 0.f ? a1 : ALPHA * a1;
            const float w0 = expf(a0);
            const float w1 = expf(a1);
            atomicAdd(&attnsum[2 * dd[k]], w0);
            atomicAdd(&attnsum[2 * dd[k] + 1], w1);
            z0 += w0; z1 += w1;
        }
    }

    #pragma unroll
    for (int m = 1; m < 64; m <<= 1) {
        z0 += __shfl_xor(z0, m, 64);
        z1 += __shfl_xor(z1, m, 64);
    }
    const int wv = threadIdx.x >> 6;
    if ((threadIdx.x & 63) == 0) { zr0[wv] = z0; zr1[wv] = z1; }
    __syncthreads();
    if (threadIdx.x == 0) {
        const float t0 = zr0[0] + zr0[1] + zr0[2] + zr0[3];
        const float t1 = zr1[0] + zr1[1] + zr1[2] + zr1[3];
        atomicAdd(&Z[0], t0);
        atomicAdd(&Z[1], t1);
    }
}

// K3: split-bf16 MFMA GEMM with LDS-staged B, fused attention scaling.
__global__ __launch_bounds__(256)
void gat_node(const float* __restrict__ x, const unsigned short* __restrict__ Wf,
              const float* __restrict__ attnsum, const float* __restrict__ Z,
              float* __restrict__ out)
{
    __shared__ unsigned short WsL[32768];   // 64 KB: 8 B-tiles hi | 8 lo
    const int tid = threadIdx.x;
    const int lane = tid & 63;
    const int wv = tid >> 6;
    const int lm = lane & 15;
    const int quad = lane >> 4;

    {   // stage B-fragments global -> LDS (plain copy)
        const float4* gsrc = (const float4*)Wf;   // 4096 float4
        float4* ldst = (float4*)WsL;
        #pragma unroll
        for (int i = 0; i < 16; ++i)
            ldst[i * 256 + tid] = gsrc[i * 256 + tid];
    }

    const float rz0 = 1.0f / Z[0];
    const float rz1 = 1.0f / Z[1];

    const int rowA0 = blockIdx.x * 128 + wv * 32 + lm;   // m-tile 0
    const int rowA1 = rowA0 + 16;                        // m-tile 1
    const int rc0 = rowA0 < NN ? rowA0 : NN - 1;
    const int rc1 = rowA1 < NN ? rowA1 : NN - 1;
    const float* xp0 = x + (size_t)rc0 * INF + quad * 8;
    const float* xp1 = x + (size_t)rc1 * INF + quad * 8;

    f32x4 acc[2][8];
    #pragma unroll
    for (int mi = 0; mi < 2; ++mi)
        #pragma unroll
        for (int nt = 0; nt < 8; ++nt) acc[mi][nt] = (f32x4)0.0f;

    __syncthreads();

    #pragma unroll
    for (int ks = 0; ks < 4; ++ks) {
        s16x8 ah0, al0, ah1, al1;
        {
            const float4 u0 = *(const float4*)(xp0 + ks * 32);
            const float4 v0 = *(const float4*)(xp0 + ks * 32 + 4);
            split8(u0, v0, ah0, al0);
            const float4 u1 = *(const float4*)(xp1 + ks * 32);
            const float4 v1 = *(const float4*)(xp1 + ks * 32 + 4);
            split8(u1, v1, ah1, al1);
        }
        #pragma unroll
        for (int nt = 0; nt < 8; ++nt) {
            const s16x8 bh = *(const s16x8*)&WsL[((nt * 4 + ks) * 64 + lane) * 8];
            const s16x8 bl = *(const s16x8*)&WsL[16384 + ((nt * 4 + ks) * 64 + lane) * 8];
            acc[0][nt] = __builtin_amdgcn_mfma_f32_16x16x32_bf16(ah0, bh, acc[0][nt], 0, 0, 0);
            acc[0][nt] = __builtin_amdgcn_mfma_f32_16x16x32_bf16(ah0, bl, acc[0][nt], 0, 0, 0);
            acc[0][nt] = __builtin_amdgcn_mfma_f32_16x16x32_bf16(al0, bh, acc[0][nt], 0, 0, 0);
            acc[1][nt] = __builtin_amdgcn_mfma_f32_16x16x32_bf16(ah1, bh, acc[1][nt], 0, 0, 0);
            acc[1][nt] = __builtin_amdgcn_mfma_f32_16x16x32_bf16(ah1, bl, acc[1][nt], 0, 0, 0);
            acc[1][nt] = __builtin_amdgcn_mfma_f32_16x16x32_bf16(al1, bh, acc[1][nt], 0, 0, 0);
        }
    }

    // epilogue: per-row scale = attnsum[row]/Z (broadcast float2 load).
    // C/D layout: col = lane&15, row = quad*4 + reg.
    #pragma unroll
    for (int mi = 0; mi < 2; ++mi) {
        const int rowb = blockIdx.x * 128 + wv * 32 + mi * 16 + quad * 4;
        #pragma unroll
        for (int r = 0; r < 4; ++r) {
            const int rr = rowb + r;
            if (rr < NN) {
                const float2 as = *(const float2*)&attnsum[2 * rr];
                const float sc0 = as.x * rz0;
                const float sc1 = as.y * rz1;
                float* orow = out + (size_t)rr * (NH * OUTF) + lm;
                #pragma unroll
                for (int nt = 0; nt < 8; ++nt)
                    orow[nt * 16] = acc[mi][nt][r] * (nt < 4 ? sc0 : sc1);
            }
        }
    }
}

extern "C" void kernel_launch(void* const* d_in, const int* in_sizes, int n_in,
                              void* d_out, int out_size, void* d_ws, size_t ws_size,
                              hipStream_t stream)
{
    const float* x = (const float*)d_in[0];
    const float* W = (const float*)d_in[1];
    const float* a = (const float*)d_in[2];
    const int* ei = (const int*)d_in[3];
    float* out = (float*)d_out;
    float* ws = (float*)d_ws;

    float* si = ws;
    float* sj = ws + 100000;
    float* attnsum = ws + 200000;
    float* Z = ws + 400000;
    unsigned short* Wf = (unsigned short*)(ws + 400064);

    gat_prep<<<dim3(NSPREP + NWPREP), dim3(256), 0, stream>>>(
        x, W, a, si, sj, Wf, attnsum);

    gat_edge<<<dim3(NEBLK), dim3(256), 0, stream>>>(ei, si, sj, attnsum, Z);

    gat_node<<<dim3(NBNODE), dim3(256), 0, stream>>>(x, Wf, attnsum, Z, out);
}

// Round 2
// 185.167 us; speedup vs baseline: 1.5676x; 1.5676x over previous
//
#include <hip/hip_runtime.h>

#define NN 50000
#define EE 1600000
#define INF 128
#define OUTF 64
#define NH 2
#define ALPHA 0.2f

#define NSPREP 391        // sprep blocks (128 rows each)
#define NWPREP 64         // wprep blocks
#define NBNODE 391        // GEMM blocks (128 rows each)

#define HCH 16            // edge chunks
#define RNG 16            // node ranges
#define NPR (NN / RNG)    // 3125 nodes/range -> 25 KB LDS bins
#define EPC (EE / HCH)    // 100000 edges per chunk

typedef __attribute__((ext_vector_type(8))) short s16x8;
typedef __attribute__((ext_vector_type(4))) float f32x4;

__device__ __forceinline__ unsigned short bf16_rne(float f) {
    union { float f; unsigned u; } v; v.f = f;
    unsigned r = v.u + 0x7FFFu + ((v.u >> 16) & 1u);
    return (unsigned short)(r >> 16);
}
__device__ __forceinline__ float bf16_val(unsigned short h) {
    union { unsigned u; float f; } v; v.u = ((unsigned)h) << 16;
    return v.f;
}
__device__ __forceinline__ void split8(const float4 a, const float4 b,
                                       s16x8& hi, s16x8& lo) {
    const float p[8] = {a.x, a.y, a.z, a.w, b.x, b.y, b.z, b.w};
    #pragma unroll
    for (int j = 0; j < 8; ++j) {
        const unsigned short h = bf16_rne(p[j]);
        hi[j] = (short)h;
        lo[j] = (short)bf16_rne(p[j] - bf16_val(h));
    }
}

// ws layout (floats):
//   si      [0      , 100000)
//   sj      [100000 , 200000)
//   Z       [200000 , 200002)   zeroed by K1
//   Wf      [200064 , 216448)   32768 ushorts: 8 B-tiles hi | 8 lo
//   partial [216448 , 1816448)  HCH * 100000 floats (fully written by K2)

// K1: blocks [0,NSPREP)         : s_i/s_j = x.(W.a) fp32 GEMV
//     blocks [NSPREP, +NWPREP)  : W -> split-bf16 B-fragments + Z init
__global__ __launch_bounds__(256)
void gat_prep(const float* __restrict__ x, const float* __restrict__ Wg,
              const float* __restrict__ av,
              float* __restrict__ si, float* __restrict__ sj,
              unsigned short* __restrict__ Wf, float* __restrict__ Z)
{
    __shared__ float4 u4[128];   // {ui_h0, uj_h0, ui_h1, uj_h1} per k
    const int tid = threadIdx.x;

    if (blockIdx.x >= NSPREP) {           // ---- wprep + Z-zero path ----
        const int idx = (blockIdx.x - NSPREP) * 256 + tid;  // 0..16383
        if (idx < 2) Z[idx] = 0.0f;
        const int h = idx >> 13;          // W flat = h*8192 + k*64 + o
        const int k = (idx >> 6) & 127;
        const int o = idx & 63;
        const float w = Wg[idx];
        const unsigned short hi = bf16_rne(w);
        const unsigned short lo = bf16_rne(w - bf16_val(hi));
        const int n  = h * 64 + o;        // fused col (head-major)
        const int nt = n >> 4;
        const int ks = k >> 5;
        const int kk = k & 31;
        const int ln = (kk >> 3) * 16 + (n & 15);
        const int pos = ((nt * 4 + ks) * 64 + ln) * 8 + (kk & 7);
        Wf[pos] = hi;
        Wf[16384 + pos] = lo;
        return;
    }

    // ---- sprep path: scores via u = W.a (per-block, L2-hot) ----
    if (tid < 128) {
        const int k = tid;
        float u0 = 0.f, u1 = 0.f, u2 = 0.f, u3 = 0.f;
        #pragma unroll 4
        for (int o = 0; o < 64; o += 4) {
            const float4 w0 = *(const float4*)&Wg[k * 64 + o];
            const float4 w1 = *(const float4*)&Wg[8192 + k * 64 + o];
            const float4 ai0 = *(const float4*)&av[o];
            const float4 aj0 = *(const float4*)&av[64 + o];
            const float4 ai1 = *(const float4*)&av[128 + o];
            const float4 aj1 = *(const float4*)&av[192 + o];
            u0 += w0.x*ai0.x + w0.y*ai0.y + w0.z*ai0.z + w0.w*ai0.w;
            u1 += w0.x*aj0.x + w0.y*aj0.y + w0.z*aj0.z + w0.w*aj0.w;
            u2 += w1.x*ai1.x + w1.y*ai1.y + w1.z*ai1.z + w1.w*ai1.w;
            u3 += w1.x*aj1.x + w1.y*aj1.y + w1.z*aj1.z + w1.w*aj1.w;
        }
        u4[k] = make_float4(u0, u1, u2, u3);
    }
    __syncthreads();

    const int lane = tid & 63;
    const int wv = tid >> 6;
    const int lm = lane & 15;
    const int rsub = lane >> 4;           // 4 rows per wave

    #pragma unroll
    for (int p = 0; p < 8; ++p) {         // 128 rows/block
        const int row = blockIdx.x * 128 + p * 16 + wv * 4 + rsub;
        const int rc = row < NN ? row : NN - 1;
        const float4 xa = *(const float4*)(x + (size_t)rc * INF + lm * 8);
        const float4 xb = *(const float4*)(x + (size_t)rc * INF + lm * 8 + 4);
        float s0 = 0.f, s1 = 0.f, s2 = 0.f, s3 = 0.f;
        const float xv[8] = {xa.x, xa.y, xa.z, xa.w, xb.x, xb.y, xb.z, xb.w};
        #pragma unroll
        for (int j = 0; j < 8; ++j) {
            const float4 u = u4[lm * 8 + j];
            s0 = fmaf(xv[j], u.x, s0);
            s1 = fmaf(xv[j], u.y, s1);
            s2 = fmaf(xv[j], u.z, s2);
            s3 = fmaf(xv[j], u.w, s3);
        }
        #pragma unroll
        for (int m = 1; m < 16; m <<= 1) {
            s0 += __shfl_xor(s0, m, 64);
            s1 += __shfl_xor(s1, m, 64);
            s2 += __shfl_xor(s2, m, 64);
            s3 += __shfl_xor(s3, m, 64);
        }
        if (lm == 0 && row < NN) {
            *(float2*)&si[2 * row] = make_float2(s0, s2);
            *(float2*)&sj[2 * row] = make_float2(s1, s3);
        }
    }
}

// K2: filter-on-read histogram. Block (c,r) streams edge chunk c, keeps
// edges with dst in range r, accumulates exp(e) into LDS bins, flushes the
// 3125-node slice to partial[c] + one Z atomic pair.
// Linear block id = c + HCH*r -> all 16 range-blocks of chunk c land on the
// same XCD (id mod 8 == c mod 8): chunk fetched from HBM once, 16x re-read
// served from that XCD's L2.
__global__ __launch_bounds__(512)
void gat_hist(const int* __restrict__ ei,
              const float* __restrict__ si, const float* __restrict__ sj,
              float* __restrict__ partial, float* __restrict__ Z)
{
    __shared__ float bins[NPR * 2];   // 25 KB
    __shared__ float zr0[8], zr1[8];
    const int c = blockIdx.x;
    const int r = blockIdx.y;
    const int nlo = r * NPR;

    for (int i = threadIdx.x; i < NPR; i += 512)
        ((float2*)bins)[i] = make_float2(0.f, 0.f);
    __syncthreads();

    const int4* src4 = (const int4*)(ei + (size_t)c * EPC);
    const int4* dst4 = (const int4*)(ei + EE + (size_t)c * EPC);

    float z0 = 0.f, z1 = 0.f;
    for (int i = threadIdx.x; i < EPC / 4; i += 512) {
        const int4 d4 = dst4[i];
        const int4 s4 = src4[i];
        const int dd[4] = {d4.x, d4.y, d4.z, d4.w};
        const int ss[4] = {s4.x, s4.y, s4.z, s4.w};
        #pragma unroll
        for (int k = 0; k < 4; ++k) {
            const unsigned d = (unsigned)dd[k];
            const unsigned rr = d / (unsigned)NPR;     // magic-mul
            if (rr == (unsigned)r) {
                const int rel = (int)(d - rr * (unsigned)NPR);
                const float2 vi = *(const float2*)&si[2 * ss[k]];
                const float2 vj = *(const float2*)&sj[2 * (nlo + rel)];
                float a0 = vi.x + vj.x; a0 = a0 > 0.f ? a0 : ALPHA * a0;
                float a1 = vi.y + vj.y; a1 = a1 > 0.f ? a1 : ALPHA * a1;
                const float w0 = expf(a0);
                const float w1 = expf(a1);
                atomicAdd(&bins[2 * rel], w0);
                atomicAdd(&bins[2 * rel + 1], w1);
                z0 += w0; z1 += w1;
            }
        }
    }

    #pragma unroll
    for (int m = 1; m < 64; m <<= 1) {
        z0 += __shfl_xor(z0, m, 64);
        z1 += __shfl_xor(z1, m, 64);
    }
    const int wv = threadIdx.x >> 6;
    if ((threadIdx.x & 63) == 0) { zr0[wv] = z0; zr1[wv] = z1; }
    __syncthreads();
    if (threadIdx.x == 0) {
        float t0 = 0.f, t1 = 0.f;
        #pragma unroll
        for (int i = 0; i < 8; ++i) { t0 += zr0[i]; t1 += zr1[i]; }
        atomicAdd(&Z[0], t0);
        atomicAdd(&Z[1], t1);
    }

    float2* P = (float2*)(partial + (size_t)c * 100000 + 2 * nlo);
    for (int i = threadIdx.x; i < NPR; i += 512)
        P[i] = ((const float2*)bins)[i];
}

// K3: split-bf16 MFMA GEMM with LDS-staged B, fused attention scaling.
// Prologue reduces the 16 partial chunks for this block's 128 rows into LDS.
__global__ __launch_bounds__(256)
void gat_node(const float* __restrict__ x, const unsigned short* __restrict__ Wf,
              const float* __restrict__ partial, const float* __restrict__ Z,
              float* __restrict__ out)
{
    __shared__ unsigned short WsL[32768];   // 64 KB: 8 B-tiles hi | 8 lo
    __shared__ float asum[256];             // 2 floats per row (128 rows)
    const int tid = threadIdx.x;
    const int lane = tid & 63;
    const int wv = tid >> 6;
    const int lm = lane & 15;
    const int quad = lane >> 4;

    {   // stage B-fragments global -> LDS (plain copy)
        const float4* gsrc = (const float4*)Wf;   // 4096 float4
        float4* ldst = (float4*)WsL;
        #pragma unroll
        for (int i = 0; i < 16; ++i)
            ldst[i * 256 + tid] = gsrc[i * 256 + tid];
    }

    {   // reduce partial chunks for this block's rows (coalesced)
        const int vbase = blockIdx.x * 256;       // value idx = 2*row + head
        float s = 0.f;
        if (vbase + tid < 2 * NN) {
            #pragma unroll
            for (int cc = 0; cc < HCH; ++cc)
                s += partial[(size_t)cc * 100000 + vbase + tid];
        }
        asum[tid] = s;
    }

    const float rz0 = 1.0f / Z[0];
    const float rz1 = 1.0f / Z[1];

    const int rowA0 = blockIdx.x * 128 + wv * 32 + lm;   // m-tile 0
    const int rowA1 = rowA0 + 16;                        // m-tile 1
    const int rc0 = rowA0 < NN ? rowA0 : NN - 1;
    const int rc1 = rowA1 < NN ? rowA1 : NN - 1;
    const float* xp0 = x + (size_t)rc0 * INF + quad * 8;
    const float* xp1 = x + (size_t)rc1 * INF + quad * 8;

    f32x4 acc[2][8];
    #pragma unroll
    for (int mi = 0; mi < 2; ++mi)
        #pragma unroll
        for (int nt = 0; nt < 8; ++nt) acc[mi][nt] = (f32x4)0.0f;

    __syncthreads();

    #pragma unroll
    for (int ks = 0; ks < 4; ++ks) {
        s16x8 ah0, al0, ah1, al1;
        {
            const float4 u0 = *(const float4*)(xp0 + ks * 32);
            const float4 v0 = *(const float4*)(xp0 + ks * 32 + 4);
            split8(u0, v0, ah0, al0);
            const float4 u1 = *(const float4*)(xp1 + ks * 32);
            const float4 v1 = *(const float4*)(xp1 + ks * 32 + 4);
            split8(u1, v1, ah1, al1);
        }
        #pragma unroll
        for (int nt = 0; nt < 8; ++nt) {
            const s16x8 bh = *(const s16x8*)&WsL[((nt * 4 + ks) * 64 + lane) * 8];
            const s16x8 bl = *(const s16x8*)&WsL[16384 + ((nt * 4 + ks) * 64 + lane) * 8];
            acc[0][nt] = __builtin_amdgcn_mfma_f32_16x16x32_bf16(ah0, bh, acc[0][nt], 0, 0, 0);
            acc[0][nt] = __builtin_amdgcn_mfma_f32_16x16x32_bf16(ah0, bl, acc[0][nt], 0, 0, 0);
            acc[0][nt] = __builtin_amdgcn_mfma_f32_16x16x32_bf16(al0, bh, acc[0][nt], 0, 0, 0);
            acc[1][nt] = __builtin_amdgcn_mfma_f32_16x16x32_bf16(ah1, bh, acc[1][nt], 0, 0, 0);
            acc[1][nt] = __builtin_amdgcn_mfma_f32_16x16x32_bf16(ah1, bl, acc[1][nt], 0, 0, 0);
            acc[1][nt] = __builtin_amdgcn_mfma_f32_16x16x32_bf16(al1, bh, acc[1][nt], 0, 0, 0);
        }
    }

    // epilogue: per-row scale = asum[row]/Z from LDS.
    // C/D layout: col = lane&15, row = quad*4 + reg.
    #pragma unroll
    for (int mi = 0; mi < 2; ++mi) {
        const int rowoffb = wv * 32 + mi * 16 + quad * 4;
        const int rowb = blockIdx.x * 128 + rowoffb;
        #pragma unroll
        for (int r = 0; r < 4; ++r) {
            const int rr = rowb + r;
            if (rr < NN) {
                const float sc0 = asum[2 * (rowoffb + r)] * rz0;
                const float sc1 = asum[2 * (rowoffb + r) + 1] * rz1;
                float* orow = out + (size_t)rr * (NH * OUTF) + lm;
                #pragma unroll
                for (int nt = 0; nt < 8; ++nt)
                    orow[nt * 16] = acc[mi][nt][r] * (nt < 4 ? sc0 : sc1);
            }
        }
    }
}

extern "C" void kernel_launch(void* const* d_in, const int* in_sizes, int n_in,
                              void* d_out, int out_size, void* d_ws, size_t ws_size,
                              hipStream_t stream)
{
    const float* x = (const float*)d_in[0];
    const float* W = (const float*)d_in[1];
    const float* a = (const float*)d_in[2];
    const int* ei = (const int*)d_in[3];
    float* out = (float*)d_out;
    float* ws = (float*)d_ws;

    float* si = ws;
    float* sj = ws + 100000;
    float* Z = ws + 200000;
    unsigned short* Wf = (unsigned short*)(ws + 200064);
    float* partial = ws + 216448;

    gat_prep<<<dim3(NSPREP + NWPREP), dim3(256), 0, stream>>>(
        x, W, a, si, sj, Wf, Z);

    gat_hist<<<dim3(HCH, RNG), dim3(512), 0, stream>>>(ei, si, sj, partial, Z);

    gat_node<<<dim3(NBNODE), dim3(256), 0, stream>>>(x, Wf, partial, Z, out);
}

// Round 3
// 166.084 us; speedup vs baseline: 1.7477x; 1.1149x over previous
//
#include <hip/hip_runtime.h>

#define NN 50000
#define EE 1600000
#define INF 128
#define OUTF 64
#define NH 2
#define ALPHA 0.2f

#define NSPREP 391        // sprep blocks (128 rows each)
#define NWPREP 64         // wprep blocks
#define NBNODE 391        // GEMM blocks (128 rows each)

#define HCH 32            // edge chunks
#define RNG 16            // node ranges
#define NPR (NN / RNG)    // 3125 nodes/range -> 25 KB LDS bins
#define EPC (EE / HCH)    // 50000 edges per chunk
#define NI4 (EPC / 4)     // 12500 int4 groups per chunk
#define NITER ((NI4 + 511) / 512)   // 25 outer iterations
#define QCAP 4096         // LDS queue entries (16 KB); mean fill 1024/period

typedef __attribute__((ext_vector_type(8))) short s16x8;
typedef __attribute__((ext_vector_type(4))) float f32x4;

__device__ __forceinline__ unsigned short bf16_rne(float f) {
    union { float f; unsigned u; } v; v.f = f;
    unsigned r = v.u + 0x7FFFu + ((v.u >> 16) & 1u);
    return (unsigned short)(r >> 16);
}
__device__ __forceinline__ float bf16_val(unsigned short h) {
    union { unsigned u; float f; } v; v.u = ((unsigned)h) << 16;
    return v.f;
}
__device__ __forceinline__ void split8(const float4 a, const float4 b,
                                       s16x8& hi, s16x8& lo) {
    const float p[8] = {a.x, a.y, a.z, a.w, b.x, b.y, b.z, b.w};
    #pragma unroll
    for (int j = 0; j < 8; ++j) {
        const unsigned short h = bf16_rne(p[j]);
        hi[j] = (short)h;
        lo[j] = (short)bf16_rne(p[j] - bf16_val(h));
    }
}

// ws layout (floats):
//   si      [0      , 100000)
//   sj      [100000 , 200000)
//   Z       [200000 , 200002)   zeroed by K1
//   Wf      [200064 , 216448)   32768 ushorts: 8 B-tiles hi | 8 lo
//   partial [216448 , 3416448)  HCH * 100000 floats (fully written by K2)

// K1: blocks [0,NSPREP)         : s_i/s_j = x.(W.a) fp32 GEMV
//     blocks [NSPREP, +NWPREP)  : W -> split-bf16 B-fragments + Z init
__global__ __launch_bounds__(256)
void gat_prep(const float* __restrict__ x, const float* __restrict__ Wg,
              const float* __restrict__ av,
              float* __restrict__ si, float* __restrict__ sj,
              unsigned short* __restrict__ Wf, float* __restrict__ Z)
{
    __shared__ float4 u4[128];   // {ui_h0, uj_h0, ui_h1, uj_h1} per k
    const int tid = threadIdx.x;

    if (blockIdx.x >= NSPREP) {           // ---- wprep + Z-zero path ----
        const int idx = (blockIdx.x - NSPREP) * 256 + tid;  // 0..16383
        if (idx < 2) Z[idx] = 0.0f;
        const int h = idx >> 13;          // W flat = h*8192 + k*64 + o
        const int k = (idx >> 6) & 127;
        const int o = idx & 63;
        const float w = Wg[idx];
        const unsigned short hi = bf16_rne(w);
        const unsigned short lo = bf16_rne(w - bf16_val(hi));
        const int n  = h * 64 + o;        // fused col (head-major)
        const int nt = n >> 4;
        const int ks = k >> 5;
        const int kk = k & 31;
        const int ln = (kk >> 3) * 16 + (n & 15);
        const int pos = ((nt * 4 + ks) * 64 + ln) * 8 + (kk & 7);
        Wf[pos] = hi;
        Wf[16384 + pos] = lo;
        return;
    }

    // ---- sprep path: scores via u = W.a (per-block, L2-hot) ----
    if (tid < 128) {
        const int k = tid;
        float u0 = 0.f, u1 = 0.f, u2 = 0.f, u3 = 0.f;
        #pragma unroll 4
        for (int o = 0; o < 64; o += 4) {
            const float4 w0 = *(const float4*)&Wg[k * 64 + o];
            const float4 w1 = *(const float4*)&Wg[8192 + k * 64 + o];
            const float4 ai0 = *(const float4*)&av[o];
            const float4 aj0 = *(const float4*)&av[64 + o];
            const float4 ai1 = *(const float4*)&av[128 + o];
            const float4 aj1 = *(const float4*)&av[192 + o];
            u0 += w0.x*ai0.x + w0.y*ai0.y + w0.z*ai0.z + w0.w*ai0.w;
            u1 += w0.x*aj0.x + w0.y*aj0.y + w0.z*aj0.z + w0.w*aj0.w;
            u2 += w1.x*ai1.x + w1.y*ai1.y + w1.z*ai1.z + w1.w*ai1.w;
            u3 += w1.x*aj1.x + w1.y*aj1.y + w1.z*aj1.z + w1.w*aj1.w;
        }
        u4[k] = make_float4(u0, u1, u2, u3);
    }
    __syncthreads();

    const int lane = tid & 63;
    const int wv = tid >> 6;
    const int lm = lane & 15;
    const int rsub = lane >> 4;           // 4 rows per wave

    #pragma unroll
    for (int p = 0; p < 8; ++p) {         // 128 rows/block
        const int row = blockIdx.x * 128 + p * 16 + wv * 4 + rsub;
        const int rc = row < NN ? row : NN - 1;
        const float4 xa = *(const float4*)(x + (size_t)rc * INF + lm * 8);
        const float4 xb = *(const float4*)(x + (size_t)rc * INF + lm * 8 + 4);
        float s0 = 0.f, s1 = 0.f, s2 = 0.f, s3 = 0.f;
        const float xv[8] = {xa.x, xa.y, xa.z, xa.w, xb.x, xb.y, xb.z, xb.w};
        #pragma unroll
        for (int j = 0; j < 8; ++j) {
            const float4 u = u4[lm * 8 + j];
            s0 = fmaf(xv[j], u.x, s0);
            s1 = fmaf(xv[j], u.y, s1);
            s2 = fmaf(xv[j], u.z, s2);
            s3 = fmaf(xv[j], u.w, s3);
        }
        #pragma unroll
        for (int m = 1; m < 16; m <<= 1) {
            s0 += __shfl_xor(s0, m, 64);
            s1 += __shfl_xor(s1, m, 64);
            s2 += __shfl_xor(s2, m, 64);
            s3 += __shfl_xor(s3, m, 64);
        }
        if (lm == 0 && row < NN) {
            *(float2*)&si[2 * row] = make_float2(s0, s2);
            *(float2*)&sj[2 * row] = make_float2(s1, s3);
        }
    }
}

// K2: filter-scan + ballot-compacted LDS queue + dense drain.
// Block (c,r) streams edge chunk c; scan phase only computes the range test
// and appends packed (rel<<16|src) hits to an LDS queue (wave-coherent).
// Every 8 iterations the queue is drained densely: all lanes do the
// gather/exp/bin-atomic work at full occupancy. Full per-edge work thus
// executes 1.6M times (not 25.6M).
__global__ __launch_bounds__(512)
void gat_hist(const int* __restrict__ ei,
              const float* __restrict__ si, const float* __restrict__ sj,
              float* __restrict__ partial, float* __restrict__ Z)
{
    __shared__ float bins[NPR * 2];   // 25 KB
    __shared__ unsigned q[QCAP];      // 16 KB
    __shared__ int qcnt;
    __shared__ float zr0[8], zr1[8];
    const int c = blockIdx.x;
    const int r = blockIdx.y;
    const int nlo = r * NPR;
    const int tid = threadIdx.x;

    for (int i = tid; i < NPR; i += 512)
        ((float2*)bins)[i] = make_float2(0.f, 0.f);
    if (tid == 0) qcnt = 0;
    __syncthreads();

    const int4* src4 = (const int4*)(ei + (size_t)c * EPC);
    const int4* dst4 = (const int4*)(ei + EE + (size_t)c * EPC);

    float z0 = 0.f, z1 = 0.f;
    for (int j = 0; j < NITER; ++j) {
        const int i = j * 512 + tid;
        int4 d4 = make_int4(-1, -1, -1, -1);
        int4 s4 = make_int4(0, 0, 0, 0);
        if (i < NI4) { d4 = dst4[i]; s4 = src4[i]; }
        const int dd[4] = {d4.x, d4.y, d4.z, d4.w};
        const int ss[4] = {s4.x, s4.y, s4.z, s4.w};
        #pragma unroll
        for (int k = 0; k < 4; ++k) {
            const unsigned d = (unsigned)dd[k];
            const unsigned rr = d / (unsigned)NPR;     // magic-mul
            const bool pass = (rr == (unsigned)r);
            const unsigned long long m = __ballot(pass);
            const int cnt = __popcll(m);
            const unsigned pre = __builtin_amdgcn_mbcnt_hi(
                (unsigned)(m >> 32),
                __builtin_amdgcn_mbcnt_lo((unsigned)(m & 0xffffffffu), 0u));
            int base = 0;
            if ((tid & 63) == 0) base = atomicAdd(&qcnt, cnt);
            base = __shfl(base, 0, 64);
            if (pass) {
                const int pos = base + (int)pre;
                if (pos < QCAP)
                    q[pos] = (unsigned)ss[k] | ((d - rr * (unsigned)NPR) << 16);
            }
        }

        if ((j & 7) == 7 || j == NITER - 1) {      // ---- dense drain ----
            __syncthreads();
            const int qn = min(qcnt, QCAP);
            for (int t = tid; t < qn; t += 512) {
                const unsigned pk = q[t];
                const int s = (int)(pk & 0xFFFFu);
                const int rel = (int)(pk >> 16);
                const float2 vi = *(const float2*)&si[2 * s];
                const float2 vj = *(const float2*)&sj[2 * (nlo + rel)];
                float a0 = vi.x + vj.x; a0 = a0 > 0.f ? a0 : ALPHA * a0;
                float a1 = vi.y + vj.y; a1 = a1 > 0.f ? a1 : ALPHA * a1;
                const float w0 = expf(a0);
                const float w1 = expf(a1);
                atomicAdd(&bins[2 * rel], w0);
                atomicAdd(&bins[2 * rel + 1], w1);
                z0 += w0; z1 += w1;
            }
            __syncthreads();
            if (tid == 0) qcnt = 0;
            __syncthreads();
        }
    }

    #pragma unroll
    for (int m = 1; m < 64; m <<= 1) {
        z0 += __shfl_xor(z0, m, 64);
        z1 += __shfl_xor(z1, m, 64);
    }
    const int wv = tid >> 6;
    if ((tid & 63) == 0) { zr0[wv] = z0; zr1[wv] = z1; }
    __syncthreads();
    if (tid == 0) {
        float t0 = 0.f, t1 = 0.f;
        #pragma unroll
        for (int i = 0; i < 8; ++i) { t0 += zr0[i]; t1 += zr1[i]; }
        atomicAdd(&Z[0], t0);
        atomicAdd(&Z[1], t1);
    }

    float2* P = (float2*)(partial + (size_t)c * 100000 + 2 * nlo);
    for (int i = tid; i < NPR; i += 512)
        P[i] = ((const float2*)bins)[i];
}

// K3: split-bf16 MFMA GEMM with LDS-staged B, fused attention scaling.
// Prologue reduces the partial chunks for this block's 128 rows into LDS.
__global__ __launch_bounds__(256)
void gat_node(const float* __restrict__ x, const unsigned short* __restrict__ Wf,
              const float* __restrict__ partial, const float* __restrict__ Z,
              float* __restrict__ out)
{
    __shared__ unsigned short WsL[32768];   // 64 KB: 8 B-tiles hi | 8 lo
    __shared__ float asum[256];             // 2 floats per row (128 rows)
    const int tid = threadIdx.x;
    const int lane = tid & 63;
    const int wv = tid >> 6;
    const int lm = lane & 15;
    const int quad = lane >> 4;

    {   // stage B-fragments global -> LDS (plain copy)
        const float4* gsrc = (const float4*)Wf;   // 4096 float4
        float4* ldst = (float4*)WsL;
        #pragma unroll
        for (int i = 0; i < 16; ++i)
            ldst[i * 256 + tid] = gsrc[i * 256 + tid];
    }

    {   // reduce partial chunks for this block's rows (coalesced)
        const int vbase = blockIdx.x * 256;       // value idx = 2*row + head
        float s = 0.f;
        if (vbase + tid < 2 * NN) {
            #pragma unroll
            for (int cc = 0; cc < HCH; ++cc)
                s += partial[(size_t)cc * 100000 + vbase + tid];
        }
        asum[tid] = s;
    }

    const float rz0 = 1.0f / Z[0];
    const float rz1 = 1.0f / Z[1];

    const int rowA0 = blockIdx.x * 128 + wv * 32 + lm;   // m-tile 0
    const int rowA1 = rowA0 + 16;                        // m-tile 1
    const int rc0 = rowA0 < NN ? rowA0 : NN - 1;
    const int rc1 = rowA1 < NN ? rowA1 : NN - 1;
    const float* xp0 = x + (size_t)rc0 * INF + quad * 8;
    const float* xp1 = x + (size_t)rc1 * INF + quad * 8;

    f32x4 acc[2][8];
    #pragma unroll
    for (int mi = 0; mi < 2; ++mi)
        #pragma unroll
        for (int nt = 0; nt < 8; ++nt) acc[mi][nt] = (f32x4)0.0f;

    __syncthreads();

    #pragma unroll
    for (int ks = 0; ks < 4; ++ks) {
        s16x8 ah0, al0, ah1, al1;
        {
            const float4 u0 = *(const float4*)(xp0 + ks * 32);
            const float4 v0 = *(const float4*)(xp0 + ks * 32 + 4);
            split8(u0, v0, ah0, al0);
            const float4 u1 = *(const float4*)(xp1 + ks * 32);
            const float4 v1 = *(const float4*)(xp1 + ks * 32 + 4);
            split8(u1, v1, ah1, al1);
        }
        #pragma unroll
        for (int nt = 0; nt < 8; ++nt) {
            const s16x8 bh = *(const s16x8*)&WsL[((nt * 4 + ks) * 64 + lane) * 8];
            const s16x8 bl = *(const s16x8*)&WsL[16384 + ((nt * 4 + ks) * 64 + lane) * 8];
            acc[0][nt] = __builtin_amdgcn_mfma_f32_16x16x32_bf16(ah0, bh, acc[0][nt], 0, 0, 0);
            acc[0][nt] = __builtin_amdgcn_mfma_f32_16x16x32_bf16(ah0, bl, acc[0][nt], 0, 0, 0);
            acc[0][nt] = __builtin_amdgcn_mfma_f32_16x16x32_bf16(al0, bh, acc[0][nt], 0, 0, 0);
            acc[1][nt] = __builtin_amdgcn_mfma_f32_16x16x32_bf16(ah1, bh, acc[1][nt], 0, 0, 0);
            acc[1][nt] = __builtin_amdgcn_mfma_f32_16x16x32_bf16(ah1, bl, acc[1][nt], 0, 0, 0);
            acc[1][nt] = __builtin_amdgcn_mfma_f32_16x16x32_bf16(al1, bh, acc[1][nt], 0, 0, 0);
        }
    }

    // epilogue: per-row scale = asum[row]/Z from LDS.
    // C/D layout: col = lane&15, row = quad*4 + reg.
    #pragma unroll
    for (int mi = 0; mi < 2; ++mi) {
        const int rowoffb = wv * 32 + mi * 16 + quad * 4;
        const int rowb = blockIdx.x * 128 + rowoffb;
        #pragma unroll
        for (int r = 0; r < 4; ++r) {
            const int rr = rowb + r;
            if (rr < NN) {
                const float sc0 = asum[2 * (rowoffb + r)] * rz0;
                const float sc1 = asum[2 * (rowoffb + r) + 1] * rz1;
                float* orow = out + (size_t)rr * (NH * OUTF) + lm;
                #pragma unroll
                for (int nt = 0; nt < 8; ++nt)
                    orow[nt * 16] = acc[mi][nt][r] * (nt < 4 ? sc0 : sc1);
            }
        }
    }
}

extern "C" void kernel_launch(void* const* d_in, const int* in_sizes, int n_in,
                              void* d_out, int out_size, void* d_ws, size_t ws_size,
                              hipStream_t stream)
{
    const float* x = (const float*)d_in[0];
    const float* W = (const float*)d_in[1];
    const float* a = (const float*)d_in[2];
    const int* ei = (const int*)d_in[3];
    float* out = (float*)d_out;
    float* ws = (float*)d_ws;

    float* si = ws;
    float* sj = ws + 100000;
    float* Z = ws + 200000;
    unsigned short* Wf = (unsigned short*)(ws + 200064);
    float* partial = ws + 216448;

    gat_prep<<<dim3(NSPREP + NWPREP), dim3(256), 0, stream>>>(
        x, W, a, si, sj, Wf, Z);

    gat_hist<<<dim3(HCH, RNG), dim3(512), 0, stream>>>(ei, si, sj, partial, Z);

    gat_node<<<dim3(NBNODE), dim3(256), 0, stream>>>(x, Wf, partial, Z, out);
}

// Round 4
// 140.908 us; speedup vs baseline: 2.0600x; 1.1787x over previous
//
#include <hip/hip_runtime.h>

#define NN 50000
#define EE 1600000
#define INF 128
#define OUTF 64
#define NH 2
#define ALPHA 0.2f

#define NSPREP 391        // sprep blocks (128 rows each)
#define NWPREP 64         // wprep blocks
#define NBNODE 391        // GEMM blocks (128 rows each)

#define HCH 32            // edge chunks
#define RNG 8             // node ranges
#define NPR (NN / RNG)    // 6250 nodes/range -> 50 KB LDS bins
#define EPC (EE / HCH)    // 50000 edges per chunk
#define NI4 (EPC / 4)     // 12500 int4 groups per chunk
#define HWAVES 16         // waves per hist block (1024 threads)
#define WITER ((NI4 + 1023) / 1024)   // 13 outer iterations
#define QW 512            // queue entries per wave (2 KB); drain at > QW-256

typedef __attribute__((ext_vector_type(8))) short s16x8;
typedef __attribute__((ext_vector_type(4))) float f32x4;

__device__ __forceinline__ unsigned short bf16_rne(float f) {
    union { float f; unsigned u; } v; v.f = f;
    unsigned r = v.u + 0x7FFFu + ((v.u >> 16) & 1u);
    return (unsigned short)(r >> 16);
}
__device__ __forceinline__ float bf16_val(unsigned short h) {
    union { unsigned u; float f; } v; v.u = ((unsigned)h) << 16;
    return v.f;
}
__device__ __forceinline__ void split8(const float4 a, const float4 b,
                                       s16x8& hi, s16x8& lo) {
    const float p[8] = {a.x, a.y, a.z, a.w, b.x, b.y, b.z, b.w};
    #pragma unroll
    for (int j = 0; j < 8; ++j) {
        const unsigned short h = bf16_rne(p[j]);
        hi[j] = (short)h;
        lo[j] = (short)bf16_rne(p[j] - bf16_val(h));
    }
}

// ws layout (floats):
//   si      [0      , 100000)
//   sj      [100000 , 200000)
//   Z       [200000 , 200002)   zeroed by K1
//   Wf      [200064 , 216448)   32768 ushorts: 8 B-tiles hi | 8 lo
//   partial [216448 , 3416448)  HCH * 100000 floats (fully written by K2)

// K1: blocks [0,NSPREP)         : s_i/s_j = x.(W.a) fp32 GEMV
//     blocks [NSPREP, +NWPREP)  : W -> split-bf16 B-fragments + Z init
__global__ __launch_bounds__(256)
void gat_prep(const float* __restrict__ x, const float* __restrict__ Wg,
              const float* __restrict__ av,
              float* __restrict__ si, float* __restrict__ sj,
              unsigned short* __restrict__ Wf, float* __restrict__ Z)
{
    __shared__ float4 u4[128];   // {ui_h0, uj_h0, ui_h1, uj_h1} per k
    const int tid = threadIdx.x;

    if (blockIdx.x >= NSPREP) {           // ---- wprep + Z-zero path ----
        const int idx = (blockIdx.x - NSPREP) * 256 + tid;  // 0..16383
        if (idx < 2) Z[idx] = 0.0f;
        const int h = idx >> 13;          // W flat = h*8192 + k*64 + o
        const int k = (idx >> 6) & 127;
        const int o = idx & 63;
        const float w = Wg[idx];
        const unsigned short hi = bf16_rne(w);
        const unsigned short lo = bf16_rne(w - bf16_val(hi));
        const int n  = h * 64 + o;        // fused col (head-major)
        const int nt = n >> 4;
        const int ks = k >> 5;
        const int kk = k & 31;
        const int ln = (kk >> 3) * 16 + (n & 15);
        const int pos = ((nt * 4 + ks) * 64 + ln) * 8 + (kk & 7);
        Wf[pos] = hi;
        Wf[16384 + pos] = lo;
        return;
    }

    // ---- sprep path: scores via u = W.a (per-block, L2-hot) ----
    if (tid < 128) {
        const int k = tid;
        float u0 = 0.f, u1 = 0.f, u2 = 0.f, u3 = 0.f;
        #pragma unroll 4
        for (int o = 0; o < 64; o += 4) {
            const float4 w0 = *(const float4*)&Wg[k * 64 + o];
            const float4 w1 = *(const float4*)&Wg[8192 + k * 64 + o];
            const float4 ai0 = *(const float4*)&av[o];
            const float4 aj0 = *(const float4*)&av[64 + o];
            const float4 ai1 = *(const float4*)&av[128 + o];
            const float4 aj1 = *(const float4*)&av[192 + o];
            u0 += w0.x*ai0.x + w0.y*ai0.y + w0.z*ai0.z + w0.w*ai0.w;
            u1 += w0.x*aj0.x + w0.y*aj0.y + w0.z*aj0.z + w0.w*aj0.w;
            u2 += w1.x*ai1.x + w1.y*ai1.y + w1.z*ai1.z + w1.w*ai1.w;
            u3 += w1.x*aj1.x + w1.y*aj1.y + w1.z*aj1.z + w1.w*aj1.w;
        }
        u4[k] = make_float4(u0, u1, u2, u3);
    }
    __syncthreads();

    const int lane = tid & 63;
    const int wv = tid >> 6;
    const int lm = lane & 15;
    const int rsub = lane >> 4;           // 4 rows per wave

    #pragma unroll
    for (int p = 0; p < 8; ++p) {         // 128 rows/block
        const int row = blockIdx.x * 128 + p * 16 + wv * 4 + rsub;
        const int rc = row < NN ? row : NN - 1;
        const float4 xa = *(const float4*)(x + (size_t)rc * INF + lm * 8);
        const float4 xb = *(const float4*)(x + (size_t)rc * INF + lm * 8 + 4);
        float s0 = 0.f, s1 = 0.f, s2 = 0.f, s3 = 0.f;
        const float xv[8] = {xa.x, xa.y, xa.z, xa.w, xb.x, xb.y, xb.z, xb.w};
        #pragma unroll
        for (int j = 0; j < 8; ++j) {
            const float4 u = u4[lm * 8 + j];
            s0 = fmaf(xv[j], u.x, s0);
            s1 = fmaf(xv[j], u.y, s1);
            s2 = fmaf(xv[j], u.z, s2);
            s3 = fmaf(xv[j], u.w, s3);
        }
        #pragma unroll
        for (int m = 1; m < 16; m <<= 1) {
            s0 += __shfl_xor(s0, m, 64);
            s1 += __shfl_xor(s1, m, 64);
            s2 += __shfl_xor(s2, m, 64);
            s3 += __shfl_xor(s3, m, 64);
        }
        if (lm == 0 && row < NN) {
            *(float2*)&si[2 * row] = make_float2(s0, s2);
            *(float2*)&sj[2 * row] = make_float2(s1, s3);
        }
    }
}

// K2: filter-scan with per-wave private LDS queues (no cross-wave sync in
// the main loop). Scan: range test + 4 independent ballots per int4; hits
// appended at qbase + wave-uniform count (popcll sums only - no LDS atomic,
// no shfl broadcast). Drain: each wave densely processes its own queue
// (gathers/exp/bin-atomics at full lane occupancy). Block-wide barriers only
// at bins-zero and final flush.
__global__ __launch_bounds__(1024)
void gat_hist(const int* __restrict__ ei,
              const float* __restrict__ si, const float* __restrict__ sj,
              float* __restrict__ partial, float* __restrict__ Z)
{
    __shared__ float bins[NPR * 2];       // 50 KB
    __shared__ unsigned q[HWAVES * QW];   // 32 KB
    __shared__ float zr0[HWAVES], zr1[HWAVES];
    const int c = blockIdx.x;
    const int r = blockIdx.y;
    const int nlo = r * NPR;
    const int tid = threadIdx.x;
    const int lane = tid & 63;
    const int wv = tid >> 6;
    const int qbase = wv * QW;

    for (int i = tid; i < NPR; i += 1024)
        ((float2*)bins)[i] = make_float2(0.f, 0.f);
    __syncthreads();

    const int4* src4 = (const int4*)(ei + (size_t)c * EPC);
    const int4* dst4 = (const int4*)(ei + EE + (size_t)c * EPC);

    float z0 = 0.f, z1 = 0.f;
    int qn = 0;                            // wave-uniform queue count

    for (int j = 0; j < WITER; ++j) {
        const int i = j * 1024 + tid;
        int4 d4 = make_int4(-1, -1, -1, -1);   // sentinel: rr huge -> no pass
        int4 s4 = make_int4(0, 0, 0, 0);
        if (i < NI4) { d4 = dst4[i]; s4 = src4[i]; }
        const unsigned dd[4] = {(unsigned)d4.x, (unsigned)d4.y,
                                (unsigned)d4.z, (unsigned)d4.w};
        const unsigned ss[4] = {(unsigned)s4.x, (unsigned)s4.y,
                                (unsigned)s4.z, (unsigned)s4.w};

        unsigned rel[4]; bool pass[4];
        #pragma unroll
        for (int k = 0; k < 4; ++k) {
            const unsigned rr = dd[k] / (unsigned)NPR;   // magic-mul
            pass[k] = (rr == (unsigned)r);
            rel[k] = dd[k] - rr * (unsigned)NPR;
        }
        unsigned long long m[4];
        #pragma unroll
        for (int k = 0; k < 4; ++k) m[k] = __ballot(pass[k]);

        int cbase = qn;
        #pragma unroll
        for (int k = 0; k < 4; ++k) {
            const unsigned pre = __builtin_amdgcn_mbcnt_hi(
                (unsigned)(m[k] >> 32),
                __builtin_amdgcn_mbcnt_lo((unsigned)(m[k] & 0xffffffffu), 0u));
            if (pass[k])
                q[qbase + cbase + (int)pre] = ss[k] | (rel[k] << 16);
            cbase += __popcll(m[k]);
        }
        qn = cbase;

        if (qn > QW - 256 || j == WITER - 1) {   // ---- per-wave dense drain ----
            for (int t = lane; t < qn; t += 64) {
                const unsigned pk = q[qbase + t];
                const int s = (int)(pk & 0xFFFFu);
                const int rl = (int)(pk >> 16);
                const float2 vi = *(const float2*)&si[2 * s];
                const float2 vj = *(const float2*)&sj[2 * (nlo + rl)];
                float a0 = vi.x + vj.x; a0 = a0 > 0.f ? a0 : ALPHA * a0;
                float a1 = vi.y + vj.y; a1 = a1 > 0.f ? a1 : ALPHA * a1;
                const float w0 = expf(a0);
                const float w1 = expf(a1);
                atomicAdd(&bins[2 * rl], w0);
                atomicAdd(&bins[2 * rl + 1], w1);
                z0 += w0; z1 += w1;
            }
            qn = 0;
        }
    }

    #pragma unroll
    for (int m = 1; m < 64; m <<= 1) {
        z0 += __shfl_xor(z0, m, 64);
        z1 += __shfl_xor(z1, m, 64);
    }
    if (lane == 0) { zr0[wv] = z0; zr1[wv] = z1; }
    __syncthreads();
    if (tid == 0) {
        float t0 = 0.f, t1 = 0.f;
        #pragma unroll
        for (int i = 0; i < HWAVES; ++i) { t0 += zr0[i]; t1 += zr1[i]; }
        atomicAdd(&Z[0], t0);
        atomicAdd(&Z[1], t1);
    }

    float2* P = (float2*)(partial + (size_t)c * 100000 + 2 * nlo);
    for (int i = tid; i < NPR; i += 1024)
        P[i] = ((const float2*)bins)[i];
}

// K3: split-bf16 MFMA GEMM with LDS-staged B, fused attention scaling.
// Prologue reduces the partial chunks for this block's 128 rows into LDS.
__global__ __launch_bounds__(256)
void gat_node(const float* __restrict__ x, const unsigned short* __restrict__ Wf,
              const float* __restrict__ partial, const float* __restrict__ Z,
              float* __restrict__ out)
{
    __shared__ unsigned short WsL[32768];   // 64 KB: 8 B-tiles hi | 8 lo
    __shared__ float asum[256];             // 2 floats per row (128 rows)
    const int tid = threadIdx.x;
    const int lane = tid & 63;
    const int wv = tid >> 6;
    const int lm = lane & 15;
    const int quad = lane >> 4;

    {   // stage B-fragments global -> LDS (plain copy)
        const float4* gsrc = (const float4*)Wf;   // 4096 float4
        float4* ldst = (float4*)WsL;
        #pragma unroll
        for (int i = 0; i < 16; ++i)
            ldst[i * 256 + tid] = gsrc[i * 256 + tid];
    }

    {   // reduce partial chunks for this block's rows (coalesced)
        const int vbase = blockIdx.x * 256;       // value idx = 2*row + head
        float s = 0.f;
        if (vbase + tid < 2 * NN) {
            #pragma unroll
            for (int cc = 0; cc < HCH; ++cc)
                s += partial[(size_t)cc * 100000 + vbase + tid];
        }
        asum[tid] = s;
    }

    const float rz0 = 1.0f / Z[0];
    const float rz1 = 1.0f / Z[1];

    const int rowA0 = blockIdx.x * 128 + wv * 32 + lm;   // m-tile 0
    const int rowA1 = rowA0 + 16;                        // m-tile 1
    const int rc0 = rowA0 < NN ? rowA0 : NN - 1;
    const int rc1 = rowA1 < NN ? rowA1 : NN - 1;
    const float* xp0 = x + (size_t)rc0 * INF + quad * 8;
    const float* xp1 = x + (size_t)rc1 * INF + quad * 8;

    f32x4 acc[2][8];
    #pragma unroll
    for (int mi = 0; mi < 2; ++mi)
        #pragma unroll
        for (int nt = 0; nt < 8; ++nt) acc[mi][nt] = (f32x4)0.0f;

    __syncthreads();

    #pragma unroll
    for (int ks = 0; ks < 4; ++ks) {
        s16x8 ah0, al0, ah1, al1;
        {
            const float4 u0 = *(const float4*)(xp0 + ks * 32);
            const float4 v0 = *(const float4*)(xp0 + ks * 32 + 4);
            split8(u0, v0, ah0, al0);
            const float4 u1 = *(const float4*)(xp1 + ks * 32);
            const float4 v1 = *(const float4*)(xp1 + ks * 32 + 4);
            split8(u1, v1, ah1, al1);
        }
        #pragma unroll
        for (int nt = 0; nt < 8; ++nt) {
            const s16x8 bh = *(const s16x8*)&WsL[((nt * 4 + ks) * 64 + lane) * 8];
            const s16x8 bl = *(const s16x8*)&WsL[16384 + ((nt * 4 + ks) * 64 + lane) * 8];
            acc[0][nt] = __builtin_amdgcn_mfma_f32_16x16x32_bf16(ah0, bh, acc[0][nt], 0, 0, 0);
            acc[0][nt] = __builtin_amdgcn_mfma_f32_16x16x32_bf16(ah0, bl, acc[0][nt], 0, 0, 0);
            acc[0][nt] = __builtin_amdgcn_mfma_f32_16x16x32_bf16(al0, bh, acc[0][nt], 0, 0, 0);
            acc[1][nt] = __builtin_amdgcn_mfma_f32_16x16x32_bf16(ah1, bh, acc[1][nt], 0, 0, 0);
            acc[1][nt] = __builtin_amdgcn_mfma_f32_16x16x32_bf16(ah1, bl, acc[1][nt], 0, 0, 0);
            acc[1][nt] = __builtin_amdgcn_mfma_f32_16x16x32_bf16(al1, bh, acc[1][nt], 0, 0, 0);
        }
    }

    // epilogue: per-row scale = asum[row]/Z from LDS.
    // C/D layout: col = lane&15, row = quad*4 + reg.
    #pragma unroll
    for (int mi = 0; mi < 2; ++mi) {
        const int rowoffb = wv * 32 + mi * 16 + quad * 4;
        const int rowb = blockIdx.x * 128 + rowoffb;
        #pragma unroll
        for (int r = 0; r < 4; ++r) {
            const int rr = rowb + r;
            if (rr < NN) {
                const float sc0 = asum[2 * (rowoffb + r)] * rz0;
                const float sc1 = asum[2 * (rowoffb + r) + 1] * rz1;
                float* orow = out + (size_t)rr * (NH * OUTF) + lm;
                #pragma unroll
                for (int nt = 0; nt < 8; ++nt)
                    orow[nt * 16] = acc[mi][nt][r] * (nt < 4 ? sc0 : sc1);
            }
        }
    }
}

extern "C" void kernel_launch(void* const* d_in, const int* in_sizes, int n_in,
                              void* d_out, int out_size, void* d_ws, size_t ws_size,
                              hipStream_t stream)
{
    const float* x = (const float*)d_in[0];
    const float* W = (const float*)d_in[1];
    const float* a = (const float*)d_in[2];
    const int* ei = (const int*)d_in[3];
    float* out = (float*)d_out;
    float* ws = (float*)d_ws;

    float* si = ws;
    float* sj = ws + 100000;
    float* Z = ws + 200000;
    unsigned short* Wf = (unsigned short*)(ws + 200064);
    float* partial = ws + 216448;

    gat_prep<<<dim3(NSPREP + NWPREP), dim3(256), 0, stream>>>(
        x, W, a, si, sj, Wf, Z);

    gat_hist<<<dim3(HCH, RNG), dim3(1024), 0, stream>>>(ei, si, sj, partial, Z);

    gat_node<<<dim3(NBNODE), dim3(256), 0, stream>>>(x, Wf, partial, Z, out);
}